// Round 1
// baseline (802.028 us; speedup 1.0000x reference)
//
#include <hip/hip_runtime.h>

// SelfBiLayer: B=256, L=2048, E=64, DA=64, R=32
//   xm = x * mask
//   H  = tanh(W1 @ xm^T)        per batch: (64x64)@(64xL)
//   Q  = W2 @ H                 per batch: (32x64)@(64xL)
//   A  = exp(Q)*mask, row-normalized over L
//   out= A @ xm                 per batch: (32xL)@(Lx64)
// Normalization is a scalar per-(b,r) divide -> fold it into the epilogue:
//   acc[r][e] = sum_l a[r,l]*xm[l,e];  ssum[r] = sum_l a[r,l];  out = acc/ssum
// One block per batch (256 blocks = 1/CU), 256 threads, 8 tiles of 256 tokens.

#define B_  256
#define L_  2048
#define E_  64
#define DA_ 64
#define R_  32
#define TL_ 256
#define NT_ (L_ / TL_)

__device__ __forceinline__ float fast_tanh(float v) {
    // tanh(v) = 1 - 2/(1+exp(2v)); exact at +-inf, abs err ~1e-7 -- far below
    // the 7.6e-3 harness threshold.
    float e = __expf(2.0f * v);
    return 1.0f - 2.0f / (e + 1.0f);
}

__launch_bounds__(TL_, 1)
__global__ void selfbi_kernel(const float* __restrict__ x,
                              const float* __restrict__ mask,
                              const float* __restrict__ W1,
                              const float* __restrict__ W2,
                              float* __restrict__ out) {
    // xs pad +4 keeps float4 alignment per row; phase-B reads are same-row
    // broadcasts (<=2-way bank aliasing, free). as pad +1 -> (t+r)%32 banks.
    __shared__ float xs[TL_][E_ + 4];   // masked x tile, 69632 B
    __shared__ float as[TL_][R_ + 1];   // exp scores,    33792 B

    const int b   = blockIdx.x;
    const int tid = threadIdx.x;
    const int r_out = tid >> 3;         // 0..31
    const int e_out = (tid & 7) << 3;   // 0,8,...,56

    float acc[8] = {0.f,0.f,0.f,0.f,0.f,0.f,0.f,0.f};
    float ssum = 0.0f;                  // redundant across the 8 threads of an r-group

    for (int tile = 0; tile < NT_; ++tile) {
        const int l = tile * TL_ + tid;
        const float m = mask[b * L_ + l];
        const float* xrow = x + ((size_t)b * L_ + l) * E_;

        // Stage this token's masked row into registers (for phase A) and LDS
        // (for phase B). Global pattern: wave covers a contiguous 16 KiB span.
        float xm[E_];
        #pragma unroll
        for (int e = 0; e < E_; e += 4) {
            float4 v = *(const float4*)(xrow + e);
            v.x *= m; v.y *= m; v.z *= m; v.w *= m;
            xm[e] = v.x; xm[e + 1] = v.y; xm[e + 2] = v.z; xm[e + 3] = v.w;
            *(float4*)&xs[tid][e] = v;
        }

        // Phase A1: H = tanh(W1 @ xm).  W1 indices are wave-uniform ->
        // compiler emits s_load_dwordx16 (SGPR broadcast operand in v_fma).
        float H[DA_];
        #pragma unroll 2
        for (int d = 0; d < DA_; ++d) {
            const float* w1r = W1 + d * E_;
            float s0 = 0.f, s1 = 0.f, s2 = 0.f, s3 = 0.f;
            #pragma unroll
            for (int e = 0; e < E_; e += 4) {
                s0 = fmaf(w1r[e],     xm[e],     s0);
                s1 = fmaf(w1r[e + 1], xm[e + 1], s1);
                s2 = fmaf(w1r[e + 2], xm[e + 2], s2);
                s3 = fmaf(w1r[e + 3], xm[e + 3], s3);
            }
            H[d] = fast_tanh((s0 + s1) + (s2 + s3));
        }

        // Phase A2: a[r] = exp(W2[r] @ H) * m  -> LDS (token-major, pad+1)
        #pragma unroll 2
        for (int r = 0; r < R_; ++r) {
            const float* w2r = W2 + r * DA_;
            float s0 = 0.f, s1 = 0.f, s2 = 0.f, s3 = 0.f;
            #pragma unroll
            for (int d = 0; d < DA_; d += 4) {
                s0 = fmaf(w2r[d],     H[d],     s0);
                s1 = fmaf(w2r[d + 1], H[d + 1], s1);
                s2 = fmaf(w2r[d + 2], H[d + 2], s2);
                s3 = fmaf(w2r[d + 3], H[d + 3], s3);
            }
            as[tid][r] = __expf((s0 + s1) + (s2 + s3)) * m;
        }

        __syncthreads();

        // Phase B: acc[r_out][e_out..+7] += sum_t as[t][r_out] * xs[t][e..]
        // Per iter: 1x b32 (8-lane broadcast) + 2x b128 (2-way) + 9 VALU.
        #pragma unroll 4
        for (int t = 0; t < TL_; ++t) {
            float av = as[t][r_out];
            ssum += av;
            float4 v0 = *(const float4*)&xs[t][e_out];
            float4 v1 = *(const float4*)&xs[t][e_out + 4];
            acc[0] = fmaf(av, v0.x, acc[0]);
            acc[1] = fmaf(av, v0.y, acc[1]);
            acc[2] = fmaf(av, v0.z, acc[2]);
            acc[3] = fmaf(av, v0.w, acc[3]);
            acc[4] = fmaf(av, v1.x, acc[4]);
            acc[5] = fmaf(av, v1.y, acc[5]);
            acc[6] = fmaf(av, v1.z, acc[6]);
            acc[7] = fmaf(av, v1.w, acc[7]);
        }

        __syncthreads();   // before next tile overwrites xs/as
    }

    const float inv = 1.0f / ssum;
    float* optr = out + ((size_t)b * R_ + r_out) * E_ + e_out;
    float4 o0 = make_float4(acc[0] * inv, acc[1] * inv, acc[2] * inv, acc[3] * inv);
    float4 o1 = make_float4(acc[4] * inv, acc[5] * inv, acc[6] * inv, acc[7] * inv);
    *(float4*)optr       = o0;
    *(float4*)(optr + 4) = o1;
}

extern "C" void kernel_launch(void* const* d_in, const int* in_sizes, int n_in,
                              void* d_out, int out_size, void* d_ws, size_t ws_size,
                              hipStream_t stream) {
    const float* x    = (const float*)d_in[0];   // (B,L,E)
    const float* mask = (const float*)d_in[1];   // (B,L)
    const float* W1   = (const float*)d_in[2];   // (DA,E)
    const float* W2   = (const float*)d_in[3];   // (R,DA)
    float* out        = (float*)d_out;           // (B,R,E)

    selfbi_kernel<<<dim3(B_), dim3(TL_), 0, stream>>>(x, mask, W1, W2, out);
}

// Round 2
// 378.129 us; speedup vs baseline: 2.1210x; 2.1210x over previous
//
#include <hip/hip_runtime.h>

// SelfBiLayer: B=256, L=2048, E=64, DA=64, R=32
// Round 2: occupancy fix. Scores are per-token; only the softmax-denominator
// couples across L and it's a sum -> split L into C=8 chunks across blocks,
// write partial (acc, ssum) per (b,chunk), reduce+divide in a 2nd kernel.
// LDS cut to 51.2 KB (bf16 staging) -> 3 blocks/CU (launch_bounds(256,3)).
// Phase B: each WAVE processes tokens t%4==wave -> single-LDS-row reads per
// step = conflict-free b128/b64, 32 independent FMAs per 2 LDS reads.

#define B_  256
#define L_  2048
#define E_  64
#define DA_ 64
#define R_  32
#define C_  8      // L-chunks (blocks per batch)
#define TL_ 256    // tokens per block

__device__ __forceinline__ unsigned short f2bf(float f) {
    unsigned u = __float_as_uint(f);
    u = (u + 0x7FFFu + ((u >> 16) & 1u)) >> 16;   // RNE
    return (unsigned short)u;
}
__device__ __forceinline__ unsigned pack2(float lo, float hi) {
    return (unsigned)f2bf(lo) | ((unsigned)f2bf(hi) << 16);
}
__device__ __forceinline__ float bflo(unsigned u) { return __uint_as_float(u << 16); }
__device__ __forceinline__ float bfhi(unsigned u) { return __uint_as_float(u & 0xFFFF0000u); }

__device__ __forceinline__ float fast_tanh(float v) {
    float e = __expf(2.0f * v);
    return 1.0f - 2.0f / (e + 1.0f);
}

__launch_bounds__(TL_, 3)
__global__ void selfbi_main(const float* __restrict__ x,
                            const float* __restrict__ mask,
                            const float* __restrict__ W1,
                            const float* __restrict__ W2,
                            float* __restrict__ accp,
                            float* __restrict__ ssump) {
    // xs: bf16 masked-x tile, rows of 64 halves (128 B, b128-aligned) = 32768 B
    // as: bf16 score tile, rows padded to 36 halves (72 B, b64-aligned) = 18432 B
    // total 51200 B -> 3 blocks/CU
    __shared__ __align__(16) char smem[TL_ * 64 * 2 + TL_ * 36 * 2];
    unsigned short (*xs)[64] = (unsigned short (*)[64])smem;
    unsigned short (*as)[36] = (unsigned short (*)[36])(smem + TL_ * 64 * 2);

    const int b    = blockIdx.x;
    const int c    = blockIdx.y;
    const int tid  = threadIdx.x;
    const int wave = tid >> 6;
    const int lane = tid & 63;

    // ================= phase A: one token per thread =================
    const int l = c * TL_ + tid;
    const float m = mask[b * L_ + l];
    const float* xrow = x + ((size_t)b * L_ + l) * E_;

    float xm[E_];
    #pragma unroll
    for (int e = 0; e < E_; e += 4) {
        float4 v = *(const float4*)(xrow + e);
        v.x *= m; v.y *= m; v.z *= m; v.w *= m;
        xm[e] = v.x; xm[e + 1] = v.y; xm[e + 2] = v.z; xm[e + 3] = v.w;
    }
    // stage bf16 xm row (a is pre-masked, so phase-B product a*xm == a*x*m ok)
    #pragma unroll
    for (int g = 0; g < 8; ++g) {
        uint4 u;
        u.x = pack2(xm[8 * g + 0], xm[8 * g + 1]);
        u.y = pack2(xm[8 * g + 2], xm[8 * g + 3]);
        u.z = pack2(xm[8 * g + 4], xm[8 * g + 5]);
        u.w = pack2(xm[8 * g + 6], xm[8 * g + 7]);
        *(uint4*)&xs[tid][8 * g] = u;
    }

    // H = tanh(W1 @ xm) -- W1 row addresses wave-uniform -> s_load broadcast
    float H[DA_];
    #pragma unroll 2
    for (int d = 0; d < DA_; ++d) {
        const float* w1r = W1 + d * E_;
        float s0 = 0.f, s1 = 0.f, s2 = 0.f, s3 = 0.f;
        #pragma unroll
        for (int e = 0; e < E_; e += 4) {
            s0 = fmaf(w1r[e],     xm[e],     s0);
            s1 = fmaf(w1r[e + 1], xm[e + 1], s1);
            s2 = fmaf(w1r[e + 2], xm[e + 2], s2);
            s3 = fmaf(w1r[e + 3], xm[e + 3], s3);
        }
        H[d] = fast_tanh((s0 + s1) + (s2 + s3));
    }

    // a[r] = exp(W2[r] @ H) * m -> bf16, 4 at a time for packed b64 LDS writes
    for (int r0 = 0; r0 < R_; r0 += 4) {
        float q[4];
        #pragma unroll
        for (int rr = 0; rr < 4; ++rr) {
            const float* w2r = W2 + (r0 + rr) * DA_;
            float s0 = 0.f, s1 = 0.f, s2 = 0.f, s3 = 0.f;
            #pragma unroll
            for (int d = 0; d < DA_; d += 4) {
                s0 = fmaf(w2r[d],     H[d],     s0);
                s1 = fmaf(w2r[d + 1], H[d + 1], s1);
                s2 = fmaf(w2r[d + 2], H[d + 2], s2);
                s3 = fmaf(w2r[d + 3], H[d + 3], s3);
            }
            q[rr] = __expf((s0 + s1) + (s2 + s3)) * m;
        }
        uint2 w;
        w.x = pack2(q[0], q[1]);
        w.y = pack2(q[2], q[3]);
        *(uint2*)&as[tid][r0] = w;
    }

    __syncthreads();

    // ================= phase B: wave w handles tokens t%4==w =================
    // Per step a wave reads ONE xs row (8 eg x b128, 32 consecutive words,
    // conflict-free broadcast) and ONE as row (8 rg x b64, 16 words).
    const int rg = lane >> 3;   // r-quad: r = 4*rg + i
    const int eg = lane & 7;    // e-oct:  e = 8*eg + j
    float acc[4][8];
    #pragma unroll
    for (int i = 0; i < 4; ++i)
        #pragma unroll
        for (int j = 0; j < 8; ++j) acc[i][j] = 0.f;
    float ss[4] = {0.f, 0.f, 0.f, 0.f};

    #pragma unroll 2
    for (int i = 0; i < TL_ / 4; ++i) {
        const int t = 4 * i + wave;
        uint2 av = *(const uint2*)&as[t][4 * rg];
        uint4 xv = *(const uint4*)&xs[t][8 * eg];
        float a0 = bflo(av.x), a1 = bfhi(av.x);
        float a2 = bflo(av.y), a3 = bfhi(av.y);
        float xf[8] = { bflo(xv.x), bfhi(xv.x), bflo(xv.y), bfhi(xv.y),
                        bflo(xv.z), bfhi(xv.z), bflo(xv.w), bfhi(xv.w) };
        ss[0] += a0; ss[1] += a1; ss[2] += a2; ss[3] += a3;
        #pragma unroll
        for (int j = 0; j < 8; ++j) {
            acc[0][j] = fmaf(a0, xf[j], acc[0][j]);
            acc[1][j] = fmaf(a1, xf[j], acc[1][j]);
            acc[2][j] = fmaf(a2, xf[j], acc[2][j]);
            acc[3][j] = fmaf(a3, xf[j], acc[3][j]);
        }
    }

    __syncthreads();

    // ============ cross-wave reduce in LDS (alias xs/as regions) ============
    float* accs  = (float*)smem;                   // 4 waves * 2048 = 32768 B
    float* ssums = (float*)(smem + TL_ * 64 * 2);  // 4 waves * 32 floats
    #pragma unroll
    for (int i = 0; i < 4; ++i) {
        const int o = wave * 2048 + (4 * rg + i) * 64 + 8 * eg;
        *(float4*)&accs[o]     = make_float4(acc[i][0], acc[i][1], acc[i][2], acc[i][3]);
        *(float4*)&accs[o + 4] = make_float4(acc[i][4], acc[i][5], acc[i][6], acc[i][7]);
    }
    if (eg == 0)
        *(float4*)&ssums[wave * 32 + 4 * rg] = make_float4(ss[0], ss[1], ss[2], ss[3]);
    __syncthreads();

    // partial store: accp[b][c][2048], ssump[b][c][32]
    {
        const int o = tid * 8;
        float4 u0 = *(float4*)&accs[o];
        float4 u1 = *(float4*)&accs[2048 + o];
        float4 u2 = *(float4*)&accs[4096 + o];
        float4 u3 = *(float4*)&accs[6144 + o];
        float4 v0 = *(float4*)&accs[o + 4];
        float4 v1 = *(float4*)&accs[2048 + o + 4];
        float4 v2 = *(float4*)&accs[4096 + o + 4];
        float4 v3 = *(float4*)&accs[6144 + o + 4];
        float4 r0 = make_float4(u0.x + u1.x + u2.x + u3.x, u0.y + u1.y + u2.y + u3.y,
                                u0.z + u1.z + u2.z + u3.z, u0.w + u1.w + u2.w + u3.w);
        float4 r1 = make_float4(v0.x + v1.x + v2.x + v3.x, v0.y + v1.y + v2.y + v3.y,
                                v0.z + v1.z + v2.z + v3.z, v0.w + v1.w + v2.w + v3.w);
        float* dst = accp + ((size_t)(b * C_ + c)) * (R_ * E_) + o;
        *(float4*)dst       = r0;
        *(float4*)(dst + 4) = r1;
        if (tid < R_) {
            float s = ssums[tid] + ssums[32 + tid] + ssums[64 + tid] + ssums[96 + tid];
            ssump[(b * C_ + c) * R_ + tid] = s;
        }
    }
}

__launch_bounds__(256, 4)
__global__ void selfbi_reduce(const float* __restrict__ accp,
                              const float* __restrict__ ssump,
                              float* __restrict__ out) {
    const int of = blockIdx.x * 256 + threadIdx.x;  // flat (b,r,e)
    const int b  = of >> 11;
    const int o  = of & 2047;
    const int r  = o >> 6;
    float num = 0.f, den = 0.f;
    #pragma unroll
    for (int cc = 0; cc < C_; ++cc) {
        num += accp[((size_t)(b * C_ + cc)) * (R_ * E_) + o];
        den += ssump[(b * C_ + cc) * R_ + r];
    }
    out[of] = num / den;
}

extern "C" void kernel_launch(void* const* d_in, const int* in_sizes, int n_in,
                              void* d_out, int out_size, void* d_ws, size_t ws_size,
                              hipStream_t stream) {
    const float* x    = (const float*)d_in[0];   // (B,L,E)
    const float* mask = (const float*)d_in[1];   // (B,L)
    const float* W1   = (const float*)d_in[2];   // (DA,E)
    const float* W2   = (const float*)d_in[3];   // (R,DA)
    float* out        = (float*)d_out;           // (B,R,E)

    float* accp  = (float*)d_ws;                         // B*C*R*E fp32 = 16 MB
    float* ssump = accp + (size_t)B_ * C_ * R_ * E_;     // B*C*R fp32 = 256 KB

    selfbi_main<<<dim3(B_, C_), dim3(TL_), 0, stream>>>(x, mask, W1, W2, accp, ssump);
    selfbi_reduce<<<dim3((B_ * R_ * E_) / 256), dim3(256), 0, stream>>>(accp, ssump, out);
}

// Round 3
// 219.786 us; speedup vs baseline: 3.6491x; 1.7204x over previous
//
#include <hip/hip_runtime.h>
#include <hip/hip_bf16.h>

// SelfBiLayer B=256,L=2048,E=64,DA=64,R=32 -- MFMA version.
//   H^T = tanh(W1 @ xm^T)   (GEMM1, 16x16x32 bf16, A=W1 in regs)
//   Q^T = W2 @ H^T          (GEMM2, A=W2 in regs, B=H^T via LDS aliasing xs)
//   a   = exp(Q)*m          -> bf16 asT[r][t] (swizzled)
//   out_partial += a^T @ xm (GEMM3, A=asT, B=xT transposed copy)
// Per block: (batch b, 256-token chunk c), 2 sub-chunks of 128 tokens, 4 waves.
// Partial (acc,ssum) per (b,c) -> reduce kernel divides.

#define B_  256
#define L_  2048
#define E_  64
#define DA_ 64
#define R_  32
#define CH_ 8      // chunks per batch
#define TL_ 128    // tokens per sub-chunk
#define NS_ 2      // sub-chunks per block

typedef __attribute__((ext_vector_type(8))) short bf16x8;
typedef __attribute__((ext_vector_type(4))) float f32x4;

// LDS layout (dword offsets). Row pitches keep b128 16-B alignment.
#define XS_WROW 36                    // xs row: 72 halves (144 B)
#define XT_WROW 68                    // xT row: 136 halves (272 B)
#define AS_WROW 68                    // asT row
#define XS_WORDS (TL_ * XS_WROW)      // 4608
#define XT_WORDS (E_ * XT_WROW)       // 4352
#define AS_WORDS (R_ * AS_WROW)       // 2176
// total smem = (4608+4352+2176+128)*4 = 45056 B -> 3 blocks/CU

__device__ __forceinline__ unsigned pk(float a, float b) {
    __hip_bfloat162 h = __float22bfloat162_rn(float2{a, b});   // v_cvt_pk_bf16_f32
    union { __hip_bfloat162 h2; unsigned u; } cv; cv.h2 = h;
    return cv.u;
}
__device__ __forceinline__ float bflo(unsigned u) { return __uint_as_float(u << 16); }
__device__ __forceinline__ float bfhi(unsigned u) { return __uint_as_float(u & 0xFFFF0000u); }
__device__ __forceinline__ float fast_tanh(float v) {
    float e = __expf(2.0f * v);
    return 1.0f - 2.0f / (e + 1.0f);
}

__launch_bounds__(256, 3)
__global__ void selfbi_main(const float* __restrict__ x,
                            const float* __restrict__ mask,
                            const float* __restrict__ W1,
                            const float* __restrict__ W2,
                            float* __restrict__ accp,
                            float* __restrict__ ssump) {
    __shared__ unsigned smem[XS_WORDS + XT_WORDS + AS_WORDS + TL_];
    unsigned* xsw = smem;                      // token-major bf16 xm / (aliased) H
    unsigned* xtw = smem + XS_WORDS;           // e-major bf16 xm (transposed)
    unsigned* asw = xtw + XT_WORDS;            // asT[r][t] bf16 scores
    float*    ms  = (float*)(asw + AS_WORDS);  // mask per token

    const int b   = blockIdx.x;
    const int c   = blockIdx.y;
    const int tid = threadIdx.x;
    const int w    = tid >> 6;
    const int lane = tid & 63;
    const int g    = lane >> 4;    // k-octet group
    const int ml   = lane & 15;    // m/n lane

    // ---- W1/W2 A-fragments in registers (A[m][k], m=lane&15, k=g*8+j) ----
    bf16x8 w1f[4][2], w2f[2][2];
    #pragma unroll
    for (int mt = 0; mt < 4; ++mt)
        #pragma unroll
        for (int kb = 0; kb < 2; ++kb) {
            const float* p = W1 + (16 * mt + ml) * E_ + 32 * kb + 8 * g;
            float4 a = *(const float4*)p, bb = *(const float4*)(p + 4);
            union { bf16x8 s; unsigned u[4]; } cv;
            cv.u[0] = pk(a.x, a.y); cv.u[1] = pk(a.z, a.w);
            cv.u[2] = pk(bb.x, bb.y); cv.u[3] = pk(bb.z, bb.w);
            w1f[mt][kb] = cv.s;
        }
    #pragma unroll
    for (int mt = 0; mt < 2; ++mt)
        #pragma unroll
        for (int kb = 0; kb < 2; ++kb) {
            const float* p = W2 + (16 * mt + ml) * DA_ + 32 * kb + 8 * g;
            float4 a = *(const float4*)p, bb = *(const float4*)(p + 4);
            union { bf16x8 s; unsigned u[4]; } cv;
            cv.u[0] = pk(a.x, a.y); cv.u[1] = pk(a.z, a.w);
            cv.u[2] = pk(bb.x, bb.y); cv.u[3] = pk(bb.z, bb.w);
            w2f[mt][kb] = cv.s;
        }

    f32x4 c3[2] = {f32x4{0,0,0,0}, f32x4{0,0,0,0}};   // out^partial C-frags
    float ssum_acc = 0.0f;

    for (int s = 0; s < NS_; ++s) {
        if (s) __syncthreads();   // protect xT/asT vs prev GEMM3/ssum readers

        // ================= staging: thread=(t=tid>>1, half) =================
        {
            const int t = tid >> 1, half = tid & 1;
            const int gl = b * L_ + c * (NS_ * TL_) + s * TL_ + t;
            const float m = mask[gl];
            if (!half) ms[t] = m;
            const float4* xr = (const float4*)(x + (size_t)gl * E_ + half * 32);
            float v[32];
            #pragma unroll
            for (int i = 0; i < 8; ++i) {
                float4 q = xr[i];
                v[4*i] = q.x * m; v[4*i+1] = q.y * m; v[4*i+2] = q.z * m; v[4*i+3] = q.w * m;
            }
            // xs: token-major bf16, word = t*36 + e/2
            #pragma unroll
            for (int i = 0; i < 4; ++i) {
                uint4 u;
                u.x = pk(v[8*i+0], v[8*i+1]); u.y = pk(v[8*i+2], v[8*i+3]);
                u.z = pk(v[8*i+4], v[8*i+5]); u.w = pk(v[8*i+6], v[8*i+7]);
                *(uint4*)&xsw[t * XS_WROW + half * 16 + 4 * i] = u;
            }
            // xT: e-major bf16, word = e*68 + ((t>>1) ^ (half<<4)), byte t&1
            #pragma unroll
            for (int j = 0; j < 32; ++j) {
                const int e = 32 * half + j;
                const int word = e * XT_WROW + ((t >> 1) ^ (half << 4));
                ((__hip_bfloat16*)&xtw[word])[t & 1] = __float2bfloat16(v[j]);
            }
        }
        // no barrier: xs/ms rows for tokens [32w,32w+32) are written by wave w itself

        // ================= GEMM1: H^T[d][t] (wave's 32 tokens) =================
        f32x4 c1[2][4];
        #pragma unroll
        for (int nt = 0; nt < 2; ++nt)
            #pragma unroll
            for (int mt = 0; mt < 4; ++mt) c1[nt][mt] = f32x4{0,0,0,0};
        #pragma unroll
        for (int kb = 0; kb < 2; ++kb)
            #pragma unroll
            for (int nt = 0; nt < 2; ++nt) {
                const int t = 32 * w + 16 * nt + ml;
                bf16x8 bfrag = *(bf16x8*)&xsw[t * XS_WROW + kb * 16 + 4 * g];
                #pragma unroll
                for (int mt = 0; mt < 4; ++mt)
                    c1[nt][mt] = __builtin_amdgcn_mfma_f32_16x16x32_bf16(
                        w1f[mt][kb], bfrag, c1[nt][mt], 0, 0, 0);
            }

        // tanh -> hs (aliases xs rows, XOR-swizzled): word = t*36 + (d2 ^ 4*(t&7))
        #pragma unroll
        for (int nt = 0; nt < 2; ++nt) {
            const int t = 32 * w + 16 * nt + ml;
            const int sw = 4 * (t & 7);
            #pragma unroll
            for (int mt = 0; mt < 4; ++mt) {
                float h0 = fast_tanh(c1[nt][mt][0]);
                float h1 = fast_tanh(c1[nt][mt][1]);
                float h2 = fast_tanh(c1[nt][mt][2]);
                float h3 = fast_tanh(c1[nt][mt][3]);
                const int d2 = 8 * mt + 2 * g;           // (16mt+4g)/2, even
                uint2 u; u.x = pk(h0, h1); u.y = pk(h2, h3);
                *(uint2*)&xsw[t * XS_WROW + (d2 ^ sw)] = u;
            }
        }

        // ================= GEMM2: Q^T[r][t] =================
        f32x4 c2[2][2];
        #pragma unroll
        for (int nt = 0; nt < 2; ++nt)
            #pragma unroll
            for (int mt = 0; mt < 2; ++mt) c2[nt][mt] = f32x4{0,0,0,0};
        #pragma unroll
        for (int kb = 0; kb < 2; ++kb)
            #pragma unroll
            for (int nt = 0; nt < 2; ++nt) {
                const int t = 32 * w + 16 * nt + ml;
                const int sw = 4 * (t & 7);
                bf16x8 bfrag = *(bf16x8*)&xsw[t * XS_WROW + ((16 * kb + 4 * g) ^ sw)];
                #pragma unroll
                for (int mt = 0; mt < 2; ++mt)
                    c2[nt][mt] = __builtin_amdgcn_mfma_f32_16x16x32_bf16(
                        w2f[mt][kb], bfrag, c2[nt][mt], 0, 0, 0);
            }

        // exp*mask -> asT[r][t] bf16: word = r*68 + ((t>>1) ^ 8*((r>>2)&3))
        #pragma unroll
        for (int nt = 0; nt < 2; ++nt) {
            const int t = 32 * w + 16 * nt + ml;
            const float mval = ms[t];
            const int tw = (t >> 1) ^ (8 * g);   // writer's g == (r>>2)&3
            #pragma unroll
            for (int mt = 0; mt < 2; ++mt)
                #pragma unroll
                for (int reg = 0; reg < 4; ++reg) {
                    const int r = 16 * mt + 4 * g + reg;
                    float a = __expf(c2[nt][mt][reg]) * mval;
                    ((__hip_bfloat16*)&asw[r * AS_WROW + tw])[t & 1] = __float2bfloat16(a);
                }
        }

        __syncthreads();   // asT + xT visible to all waves

        // ================= GEMM3: acc[r][e] += a^T @ xm =================
        {
            const int fx = (w >> 1) << 4;        // xT half-XOR const for this wave's e-tile
            const int e  = 16 * w + ml;
            const int phi = 8 * ((ml >> 2) & 3); // asT swizzle for r=16mt+ml
            #pragma unroll
            for (int kb = 0; kb < 4; ++kb) {
                bf16x8 bfrag = *(bf16x8*)&xtw[e * XT_WROW + ((16 * kb + 4 * g) ^ fx)];
                #pragma unroll
                for (int mt = 0; mt < 2; ++mt) {
                    const int r = 16 * mt + ml;
                    bf16x8 afrag = *(bf16x8*)&asw[r * AS_WROW + ((16 * kb + 4 * g) ^ phi)];
                    c3[mt] = __builtin_amdgcn_mfma_f32_16x16x32_bf16(
                        afrag, bfrag, c3[mt], 0, 0, 0);
                }
            }
        }

        // ssum partial from asT (same bf16 values as numerator)
        {
            const int rr = tid >> 3, to = tid & 7;
            const int p2 = (rr >> 2) & 3;
            const int wb = rr * AS_WROW + 8 * (to ^ p2);
            uint4 u0 = *(uint4*)&asw[wb];
            uint4 u1 = *(uint4*)&asw[wb + 4];
            float sv = bflo(u0.x) + bfhi(u0.x) + bflo(u0.y) + bfhi(u0.y)
                     + bflo(u0.z) + bfhi(u0.z) + bflo(u0.w) + bfhi(u0.w)
                     + bflo(u1.x) + bfhi(u1.x) + bflo(u1.y) + bfhi(u1.y)
                     + bflo(u1.z) + bfhi(u1.z) + bflo(u1.w) + bfhi(u1.w);
            ssum_acc += sv;
        }
    }

    // ================= epilogue =================
    float sv = ssum_acc;
    sv += __shfl_xor(sv, 1); sv += __shfl_xor(sv, 2); sv += __shfl_xor(sv, 4);

    const size_t obase = (size_t)(b * CH_ + c) * (R_ * E_);
    const int e = 16 * w + ml;
    #pragma unroll
    for (int mt = 0; mt < 2; ++mt)
        #pragma unroll
        for (int reg = 0; reg < 4; ++reg) {
            const int r = 16 * mt + 4 * g + reg;
            accp[obase + r * E_ + e] = c3[mt][reg];
        }
    if ((tid & 7) == 0) ssump[(b * CH_ + c) * R_ + (tid >> 3)] = sv;
}

__launch_bounds__(256, 4)
__global__ void selfbi_reduce(const float* __restrict__ accp,
                              const float* __restrict__ ssump,
                              float* __restrict__ out) {
    const int of = blockIdx.x * 256 + threadIdx.x;  // flat (b,r,e)
    const int b  = of >> 11;
    const int o  = of & 2047;
    const int r  = o >> 6;
    float num = 0.f, den = 0.f;
    #pragma unroll
    for (int cc = 0; cc < CH_; ++cc) {
        num += accp[((size_t)(b * CH_ + cc)) * (R_ * E_) + o];
        den += ssump[(b * CH_ + cc) * R_ + r];
    }
    out[of] = num / den;
}

extern "C" void kernel_launch(void* const* d_in, const int* in_sizes, int n_in,
                              void* d_out, int out_size, void* d_ws, size_t ws_size,
                              hipStream_t stream) {
    const float* x    = (const float*)d_in[0];   // (B,L,E)
    const float* mask = (const float*)d_in[1];   // (B,L)
    const float* W1   = (const float*)d_in[2];   // (DA,E)
    const float* W2   = (const float*)d_in[3];   // (R,DA)
    float* out        = (float*)d_out;           // (B,R,E)

    float* accp  = (float*)d_ws;                         // B*CH*R*E fp32 = 16 MB
    float* ssump = accp + (size_t)B_ * CH_ * R_ * E_;    // B*CH*R fp32

    selfbi_main<<<dim3(B_, CH_), dim3(256), 0, stream>>>(x, mask, W1, W2, accp, ssump);
    selfbi_reduce<<<dim3((B_ * R_ * E_) / 256), dim3(256), 0, stream>>>(accp, ssump, out);
}